// Round 4
// baseline (27552.246 us; speedup 1.0000x reference)
//
#include <hip/hip_runtime.h>
#include <hip/hip_bf16.h>

// Problem constants (fixed by the reference)
#define L     4096
#define E     512
#define HID   1024
#define HH    512          // H per direction
#define G4    2048         // 4*H gate rows
#define T_TAG 7
#define START_TAG 4
#define STOP_TAG  5
#define NEGV  (-10000.0f)

#define NWORK 16           // worker blocks per direction (32 units each)
#define NBLK_LAUNCH 256    // cooperative grid; ~32 blocks land on each XCD
#define SENT  0xFFFFFFFFu  // h sentinel: -NaN, unreachable for real h values

typedef unsigned int uint32x4 __attribute__((ext_vector_type(4)));

// ---------------------------------------------------------------------------
// Kernel 1: xg[t][j] = emb[sentence[t]] . w_ih[j] + b_ih[j] + b_hh[j]
// for both directions.  Tiled fp32 GEMM, tile 64x64, K-chunks of 32.
// grid (L/64, G4/64, 2), block 256.
// ---------------------------------------------------------------------------
__global__ __launch_bounds__(256)
void xg_kernel(const int* __restrict__ sentence, const float* __restrict__ emb,
               const float* __restrict__ wih_f, const float* __restrict__ bih_f,
               const float* __restrict__ bhh_f,
               const float* __restrict__ wih_b, const float* __restrict__ bih_b,
               const float* __restrict__ bhh_b,
               float* __restrict__ xg_f, float* __restrict__ xg_b)
{
    const int dir = blockIdx.z;
    const float* __restrict__ wih = dir ? wih_b : wih_f;
    const float* __restrict__ bih = dir ? bih_b : bih_f;
    const float* __restrict__ bhh = dir ? bhh_b : bhh_f;
    float* __restrict__ xg = dir ? xg_b : xg_f;

    const int t0 = blockIdx.x * 64;
    const int j0 = blockIdx.y * 64;

    __shared__ float As[32][68];
    __shared__ float Bs[32][68];
    __shared__ int   sent[64];

    const int tid = threadIdx.x;
    if (tid < 64) sent[tid] = sentence[t0 + tid];
    __syncthreads();

    const int tx = tid & 15;
    const int ty = tid >> 4;

    float acc[4][4];
#pragma unroll
    for (int a = 0; a < 4; a++)
#pragma unroll
        for (int b = 0; b < 4; b++) acc[a][b] = 0.f;

    for (int k0 = 0; k0 < E; k0 += 32) {
        __syncthreads();
#pragma unroll
        for (int q = 0; q < 2; q++) {
            const int f  = q * 256 + tid;
            const int i  = f >> 3;
            const int k4 = (f & 7) * 4;
            const float4 av = *(const float4*)(emb + (size_t)sent[i] * E + k0 + k4);
            As[k4 + 0][i] = av.x; As[k4 + 1][i] = av.y;
            As[k4 + 2][i] = av.z; As[k4 + 3][i] = av.w;
            const float4 bv = *(const float4*)(wih + (size_t)(j0 + i) * E + k0 + k4);
            Bs[k4 + 0][i] = bv.x; Bs[k4 + 1][i] = bv.y;
            Bs[k4 + 2][i] = bv.z; Bs[k4 + 3][i] = bv.w;
        }
        __syncthreads();
#pragma unroll
        for (int k = 0; k < 32; k++) {
            const float4 a4 = *(const float4*)&As[k][ty * 4];
            const float4 b4 = *(const float4*)&Bs[k][tx * 4];
            const float a[4] = { a4.x, a4.y, a4.z, a4.w };
            const float b[4] = { b4.x, b4.y, b4.z, b4.w };
#pragma unroll
            for (int ii = 0; ii < 4; ii++)
#pragma unroll
                for (int jj = 0; jj < 4; jj++) acc[ii][jj] += a[ii] * b[jj];
        }
    }

#pragma unroll
    for (int ii = 0; ii < 4; ii++) {
        const int t = t0 + ty * 4 + ii;
#pragma unroll
        for (int jj = 0; jj < 4; jj++) {
            const int j = j0 + tx * 4 + jj;
            xg[(size_t)t * G4 + j] = acc[ii][jj] + bih[j] + bhh[j];
        }
    }
}

// ---------------------------------------------------------------------------
// Kernel 2: bidirectional LSTM recurrence, XCD-local with MEASURED placement.
// 256 cooperative blocks x 512.  Each block reads its XCD via
// s_getreg(HW_REG_XCC_ID); blocks on XCD0 claim fwd worker slots 0..15 via an
// atomic counter, blocks on XCD1 claim bwd slots, everyone else exits.
// Worker owns 32 hidden units (128 gate rows).  h exchange: plain store ->
// producer-XCD L2 (shared with all same-direction consumers), sc0 (L1-bypass)
// poll loads.  Insurance: dual agent-scope store to IF + agent-scope escape
// load every 16th failed poll round (degrades instead of hanging).
// ---------------------------------------------------------------------------
__global__ __launch_bounds__(512)
void lstm_kernel(const float* __restrict__ xg_f, const float* __restrict__ xg_b,
                 const float* __restrict__ whh_f, const float* __restrict__ whh_b,
                 float* __restrict__ hf, float* __restrict__ hb, int* elect)
{
    __shared__ int s_role;
    if (threadIdx.x == 0) {
        unsigned int xcc;
        asm volatile("s_getreg_b32 %0, hwreg(HW_REG_XCC_ID)" : "=s"(xcc));
        int role = -1;
        if (xcc < 2) {
            const int r = __hip_atomic_fetch_add(&elect[xcc], 1, __ATOMIC_RELAXED,
                                                 __HIP_MEMORY_SCOPE_AGENT);
            if (r < NWORK) role = (int)(xcc * NWORK + r);
        }
        s_role = role;
    }
    __syncthreads();
    const int role = s_role;
    if (role < 0) return;
    const int dir = role >> 4;                 // 0 fwd (XCD0), 1 bwd (XCD1)
    const int rnk = role & (NWORK - 1);        // 0..15

    const float* __restrict__ xg  = dir ? xg_b  : xg_f;
    const float* __restrict__ whh = dir ? whh_b : whh_f;
    float* __restrict__ hout = dir ? hb : hf;

    const int tid  = threadIdx.x;
    const int wave = tid >> 6;        // 0..7
    const int lane = tid & 63;
    const int g    = wave >> 1;       // gate: 0=i 1=f 2=g 3=o
    const int jh   = wave & 1;        // unit half (0: 0..15, 1: 16..31)
    const int u0   = rnk * 32;
    const int col0 = lane * 8;

    // weights: w[rr][k] = whh[(g*HH + u0 + jh*16 + rr)*HH + col0 + k]
    float w[16][8];
#pragma unroll
    for (int rr = 0; rr < 16; rr++) {
        const float4* p =
            (const float4*)(whh + (size_t)(g * HH + u0 + jh * 16 + rr) * HH + col0);
        const float4 w0 = p[0], w1 = p[1];
        w[rr][0] = w0.x; w[rr][1] = w0.y; w[rr][2] = w0.z; w[rr][3] = w0.w;
        w[rr][4] = w1.x; w[rr][5] = w1.y; w[rr][6] = w1.z; w[rr][7] = w1.w;
    }

    __shared__ float glds[8][16];
    float c_state = 0.f;                       // live only for tid < 32
    const int uu = u0 + (tid & 31);

    // xg prefetch registers (gate threads only)
    float xq0 = 0.f, xq1 = 0.f, xq2 = 0.f, xq3 = 0.f;
    if (tid < 32) {
        const float* xgt = xg + (size_t)(dir ? (L - 1) : 0) * G4;
        xq0 = xgt[uu];            xq1 = xgt[HH + uu];
        xq2 = xgt[2 * HH + uu];   xq3 = xgt[3 * HH + uu];
    }

    for (int s = 0; s < L; s++) {
        const int t = dir ? (L - 1 - s) : s;

        float h[8];
        if (s == 0) {
#pragma unroll
            for (int k = 0; k < 8; k++) h[k] = 0.f;
        } else {
            const int tp = dir ? (t + 1) : (t - 1);
            const unsigned int* hp =
                (const unsigned int*)(hout + (size_t)tp * HH + col0);
            unsigned int va[8];
            int tries = 0;
            for (;;) {
                if ((tries & 15) == 15) {
                    // escape: authoritative read at the IF coherence point
#pragma unroll
                    for (int k = 0; k < 8; k++)
                        va[k] = __hip_atomic_load(hp + k, __ATOMIC_RELAXED,
                                                  __HIP_MEMORY_SCOPE_AGENT);
                } else {
                    uint32x4 a, b;
                    asm volatile("global_load_dwordx4 %0, %2, off sc0\n\t"
                                 "global_load_dwordx4 %1, %2, off offset:16 sc0\n\t"
                                 "s_waitcnt vmcnt(0)"
                                 : "=&v"(a), "=&v"(b)
                                 : "v"(hp)
                                 : "memory");
                    va[0] = a.x; va[1] = a.y; va[2] = a.z; va[3] = a.w;
                    va[4] = b.x; va[5] = b.y; va[6] = b.z; va[7] = b.w;
                }
                bool ok = true;
#pragma unroll
                for (int k = 0; k < 8; k++) ok &= (va[k] != SENT);
                if (ok) break;
                ++tries;
            }
#pragma unroll
            for (int k = 0; k < 8; k++) h[k] = __uint_as_float(va[k]);
        }

        float acc[16];
#pragma unroll
        for (int rr = 0; rr < 16; rr++) {
            float a = 0.f;
#pragma unroll
            for (int k = 0; k < 8; k++) a += w[rr][k] * h[k];
            acc[rr] = a;
        }
#pragma unroll
        for (int m = 1; m < 64; m <<= 1) {
#pragma unroll
            for (int rr = 0; rr < 16; rr++) acc[rr] += __shfl_xor(acc[rr], m, 64);
        }
        if (lane == 0) {
#pragma unroll
            for (int rr = 0; rr < 16; rr++) glds[wave][rr] = acc[rr];
        }
        __syncthreads();

        if (tid < 32) {
            const int j   = tid;         // unit within block
            const int hf_ = j >> 4;      // half
            const int rr  = j & 15;
            float iv = glds[0 + hf_][rr] + xq0;
            float fv = glds[2 + hf_][rr] + xq1;
            float gv = glds[4 + hf_][rr] + xq2;
            float ov = glds[6 + hf_][rr] + xq3;
            iv = 1.f / (1.f + expf(-iv));
            fv = 1.f / (1.f + expf(-fv));
            gv = tanhf(gv);
            ov = 1.f / (1.f + expf(-ov));
            c_state = fv * c_state + iv * gv;
            const float hv = ov * tanhf(c_state);
            const unsigned int hbits = __float_as_uint(hv);
            unsigned int* dst = (unsigned int*)&hout[(size_t)t * HH + uu];
            // fast path: plain store -> this XCD's L2 (shared with consumers)
            asm volatile("global_store_dword %0, %1, off"
                         :: "v"(dst), "v"(hbits) : "memory");
            // insurance: make it visible at the IF coherence point too
            __hip_atomic_store(dst, hbits, __ATOMIC_RELAXED,
                               __HIP_MEMORY_SCOPE_AGENT);
            // prefetch next step's xg (hides under next poll + matvec)
            if (s + 1 < L) {
                const int tn = dir ? (t - 1) : (t + 1);
                const float* xgt = xg + (size_t)tn * G4;
                xq0 = xgt[uu];            xq1 = xgt[HH + uu];
                xq2 = xgt[2 * HH + uu];   xq3 = xgt[3 * HH + uu];
            }
        }
        // no end-of-step barrier: next step's poll cannot complete before this
        // block's own producer lanes (wave 0) have stored -> glds is protected.
    }
}

// ---------------------------------------------------------------------------
// Kernel 3: feats[t][i] = [hf[t],hb[t]] . w_out[i] + b_out[i]
// grid L blocks, block 256.  feats stored with stride 8.
// ---------------------------------------------------------------------------
__global__ __launch_bounds__(256)
void feats_kernel(const float* __restrict__ hf, const float* __restrict__ hb,
                  const float* __restrict__ wout, const float* __restrict__ bout,
                  float* __restrict__ feats)
{
    const int t   = blockIdx.x;
    const int tid = threadIdx.x;

    float acc[T_TAG];
#pragma unroll
    for (int i = 0; i < T_TAG; i++) acc[i] = 0.f;

    for (int c = tid; c < HID; c += 256) {
        const float v = (c < HH) ? hf[(size_t)t * HH + c]
                                 : hb[(size_t)t * HH + (c - HH)];
#pragma unroll
        for (int i = 0; i < T_TAG; i++) acc[i] += v * wout[i * HID + c];
    }
#pragma unroll
    for (int m = 1; m < 64; m <<= 1) {
#pragma unroll
        for (int i = 0; i < T_TAG; i++) acc[i] += __shfl_xor(acc[i], m, 64);
    }

    __shared__ float red[4][T_TAG];
    const int wave = tid >> 6, lane = tid & 63;
    if (lane == 0) {
#pragma unroll
        for (int i = 0; i < T_TAG; i++) red[wave][i] = acc[i];
    }
    __syncthreads();
    if (tid < T_TAG) {
        feats[(size_t)t * 8 + tid] =
            red[0][tid] + red[1][tid] + red[2][tid] + red[3][tid] + bout[tid];
    }
}

// ---------------------------------------------------------------------------
// Kernel 4: Viterbi forward + backtrace.  One wave.
// ---------------------------------------------------------------------------
__global__ __launch_bounds__(64)
void viterbi_kernel(const float* __restrict__ feats, const float* __restrict__ trans,
                    float* __restrict__ out)
{
    __shared__ unsigned char bp[L][T_TAG];

    const int tid = threadIdx.x;     // 0..63
    const int i = tid >> 3, j = tid & 7;
    const bool valid = (i < T_TAG) && (j < T_TAG);
    const float trij = valid ? trans[i * T_TAG + j] : -1e30f;

    float fv;
    if (j < T_TAG) fv = (j == START_TAG) ? 0.f : NEGV;
    else           fv = -1e30f;

    const int ieff = (i < T_TAG) ? i : 0;
    float fq[8];
#pragma unroll
    for (int p = 0; p < 8; p++) fq[p] = feats[(size_t)p * 8 + ieff];

    for (int t = 0; t < L; t++) {
        const float sc = fv + trij;
        float best = sc; int bj = j;
#pragma unroll
        for (int m = 1; m < 8; m <<= 1) {
            const float ov = __shfl_xor(best, m, 8);
            const int   oj = __shfl_xor(bj, m, 8);
            if (ov > best || (ov == best && oj < bj)) { best = ov; bj = oj; }
        }
        const float f_t = fq[t & 7];
        if (t + 8 < L) fq[t & 7] = feats[(size_t)(t + 8) * 8 + ieff];
        const float fvnew = best + f_t;          // for dest tag == i
        if (valid && j == 0) bp[t][i] = (unsigned char)bj;
        const float nf = __shfl(fvnew, (j < T_TAG) ? j * 8 : 0, 64);
        fv = (j < T_TAG) ? nf : -1e30f;
    }

    float term = fv + ((j < T_TAG) ? trans[STOP_TAG * T_TAG + j] : -1e30f);
    float bestt = term; int bt = j;
#pragma unroll
    for (int m = 1; m < 8; m <<= 1) {
        const float ov = __shfl_xor(bestt, m, 8);
        const int   oj = __shfl_xor(bt, m, 8);
        if (ov > bestt || (ov == bestt && oj < bt)) { bestt = ov; bt = oj; }
    }

    if (tid == 0) {
        out[L] = bestt;
        int tag = bt;
        out[L - 1] = (float)tag;
        for (int t = L - 1; t >= 1; t--) {
            tag = bp[t][tag];
            out[t - 1] = (float)tag;
        }
    }
}

// ---------------------------------------------------------------------------
extern "C" void kernel_launch(void* const* d_in, const int* in_sizes, int n_in,
                              void* d_out, int out_size, void* d_ws, size_t ws_size,
                              hipStream_t stream)
{
    const int*   sentence = (const int*)  d_in[0];
    const float* emb      = (const float*)d_in[1];
    const float* wih_f    = (const float*)d_in[2];
    const float* whh_f    = (const float*)d_in[3];
    const float* bih_f    = (const float*)d_in[4];
    const float* bhh_f    = (const float*)d_in[5];
    const float* wih_b    = (const float*)d_in[6];
    const float* whh_b    = (const float*)d_in[7];
    const float* bih_b    = (const float*)d_in[8];
    const float* bhh_b    = (const float*)d_in[9];
    const float* wout     = (const float*)d_in[10];
    const float* bout     = (const float*)d_in[11];
    const float* trans    = (const float*)d_in[12];
    float* out = (float*)d_out;

    char* ws = (char*)d_ws;
    int*   elect  = (int*)ws;                                   // 1 KiB
    float* xg_f   = (float*)(ws + 1024);
    float* xg_b   = xg_f  + (size_t)L * G4;
    float* hfbuf  = xg_b  + (size_t)L * G4;
    float* hbbuf  = hfbuf + (size_t)L * HH;
    float* featsb = hbbuf + (size_t)L * HH;
    // total: 1024 + 2*L*G4*4 + 2*L*HH*4 + L*8*4  ~= 84 MB

    // election counters -> 0; h buffers -> sentinel (0xFF = -NaN)
    hipMemsetAsync(elect, 0, 1024, stream);
    hipMemsetAsync(hfbuf, 0xFF, (size_t)2 * L * HH * sizeof(float), stream);

    hipLaunchKernelGGL(xg_kernel, dim3(L / 64, G4 / 64, 2), dim3(256), 0, stream,
                       sentence, emb, wih_f, bih_f, bhh_f, wih_b, bih_b, bhh_b,
                       xg_f, xg_b);

    void* args[] = { (void*)&xg_f, (void*)&xg_b, (void*)&whh_f, (void*)&whh_b,
                     (void*)&hfbuf, (void*)&hbbuf, (void*)&elect };
    hipLaunchCooperativeKernel((void*)lstm_kernel, dim3(NBLK_LAUNCH), dim3(512),
                               args, 0, stream);

    hipLaunchKernelGGL(feats_kernel, dim3(L), dim3(256), 0, stream,
                       hfbuf, hbbuf, wout, bout, featsb);

    hipLaunchKernelGGL(viterbi_kernel, dim3(1), dim3(64), 0, stream,
                       featsb, trans, out);
}

// Round 5
// 9976.114 us; speedup vs baseline: 2.7618x; 2.7618x over previous
//
#include <hip/hip_runtime.h>
#include <hip/hip_bf16.h>

// Problem constants (fixed by the reference)
#define L     4096
#define E     512
#define HID   1024
#define HH    512          // H per direction
#define G4    2048         // 4*H gate rows
#define T_TAG 7
#define START_TAG 4
#define STOP_TAG  5
#define NEGV  (-10000.0f)

#define NBLK  16           // worker blocks per direction (32 units each)
#define SENT  0xFFFFFFFFu  // h sentinel: -NaN, unreachable for real h values

// ---------------------------------------------------------------------------
// Kernel 1: xg[t][j] = emb[sentence[t]] . w_ih[j] + b_ih[j] + b_hh[j]
// for both directions.  Tiled fp32 GEMM, tile 64x64, K-chunks of 32.
// grid (L/64, G4/64, 2), block 256.
// ---------------------------------------------------------------------------
__global__ __launch_bounds__(256)
void xg_kernel(const int* __restrict__ sentence, const float* __restrict__ emb,
               const float* __restrict__ wih_f, const float* __restrict__ bih_f,
               const float* __restrict__ bhh_f,
               const float* __restrict__ wih_b, const float* __restrict__ bih_b,
               const float* __restrict__ bhh_b,
               float* __restrict__ xg_f, float* __restrict__ xg_b)
{
    const int dir = blockIdx.z;
    const float* __restrict__ wih = dir ? wih_b : wih_f;
    const float* __restrict__ bih = dir ? bih_b : bih_f;
    const float* __restrict__ bhh = dir ? bhh_b : bhh_f;
    float* __restrict__ xg = dir ? xg_b : xg_f;

    const int t0 = blockIdx.x * 64;
    const int j0 = blockIdx.y * 64;

    __shared__ float As[32][68];
    __shared__ float Bs[32][68];
    __shared__ int   sent[64];

    const int tid = threadIdx.x;
    if (tid < 64) sent[tid] = sentence[t0 + tid];
    __syncthreads();

    const int tx = tid & 15;
    const int ty = tid >> 4;

    float acc[4][4];
#pragma unroll
    for (int a = 0; a < 4; a++)
#pragma unroll
        for (int b = 0; b < 4; b++) acc[a][b] = 0.f;

    for (int k0 = 0; k0 < E; k0 += 32) {
        __syncthreads();
#pragma unroll
        for (int q = 0; q < 2; q++) {
            const int f  = q * 256 + tid;
            const int i  = f >> 3;
            const int k4 = (f & 7) * 4;
            const float4 av = *(const float4*)(emb + (size_t)sent[i] * E + k0 + k4);
            As[k4 + 0][i] = av.x; As[k4 + 1][i] = av.y;
            As[k4 + 2][i] = av.z; As[k4 + 3][i] = av.w;
            const float4 bv = *(const float4*)(wih + (size_t)(j0 + i) * E + k0 + k4);
            Bs[k4 + 0][i] = bv.x; Bs[k4 + 1][i] = bv.y;
            Bs[k4 + 2][i] = bv.z; Bs[k4 + 3][i] = bv.w;
        }
        __syncthreads();
#pragma unroll
        for (int k = 0; k < 32; k++) {
            const float4 a4 = *(const float4*)&As[k][ty * 4];
            const float4 b4 = *(const float4*)&Bs[k][tx * 4];
            const float a[4] = { a4.x, a4.y, a4.z, a4.w };
            const float b[4] = { b4.x, b4.y, b4.z, b4.w };
#pragma unroll
            for (int ii = 0; ii < 4; ii++)
#pragma unroll
                for (int jj = 0; jj < 4; jj++) acc[ii][jj] += a[ii] * b[jj];
        }
    }

#pragma unroll
    for (int ii = 0; ii < 4; ii++) {
        const int t = t0 + ty * 4 + ii;
#pragma unroll
        for (int jj = 0; jj < 4; jj++) {
            const int j = j0 + tx * 4 + jj;
            xg[(size_t)t * G4 + j] = acc[ii][jj] + bih[j] + bhh[j];
        }
    }
}

// ---------------------------------------------------------------------------
// Kernel 2: bidirectional LSTM recurrence.  Cooperative, 32 blocks x 512.
// Blocks 0..15 = forward, 16..31 = backward.  Each block owns 32 hidden
// units (128 gate rows); W_hh slice in registers (w[16][8], 128 VGPR/lane).
// Sync = R2's proven mechanism (relaxed agent-scope atomics + NaN sentinel),
// with two fixes for its measured overheads:
//   * poll dedup: thread tid polls exactly ONE word (h[t-1][tid]) and
//     deposits it in a ping-pong LDS buffer -> 8x less IF poll traffic.
//   * register-compacting butterfly: 16-acc reduction across 64 lanes in
//     17 shuffles (vs 96), result bit-reversed over lanes 0..15.
// ---------------------------------------------------------------------------
__global__ __launch_bounds__(512)
void lstm_kernel(const float* __restrict__ xg_f, const float* __restrict__ xg_b,
                 const float* __restrict__ whh_f, const float* __restrict__ whh_b,
                 float* __restrict__ hf, float* __restrict__ hb)
{
    const int dir = blockIdx.x >> 4;           // 0 fwd, 1 bwd
    const int rnk = blockIdx.x & 15;           // 0..15

    const float* __restrict__ xg  = dir ? xg_b  : xg_f;
    const float* __restrict__ whh = dir ? whh_b : whh_f;
    float* __restrict__ hout = dir ? hb : hf;

    const int tid  = threadIdx.x;
    const int wave = tid >> 6;        // 0..7
    const int lane = tid & 63;
    const int g    = wave >> 1;       // gate: 0=i 1=f 2=g 3=o
    const int jh   = wave & 1;        // unit half (0: 0..15, 1: 16..31)
    const int u0   = rnk * 32;
    const int col0 = lane * 8;

    // weights: w[rr][k] = whh[(g*HH + u0 + jh*16 + rr)*HH + col0 + k]
    float w[16][8];
#pragma unroll
    for (int rr = 0; rr < 16; rr++) {
        const float4* p =
            (const float4*)(whh + (size_t)(g * HH + u0 + jh * 16 + rr) * HH + col0);
        const float4 w0 = p[0], w1 = p[1];
        w[rr][0] = w0.x; w[rr][1] = w0.y; w[rr][2] = w0.z; w[rr][3] = w0.w;
        w[rr][4] = w1.x; w[rr][5] = w1.y; w[rr][6] = w1.z; w[rr][7] = w1.w;
    }

    __shared__ float h_lds[2][HH];    // ping-pong h[t-1] staging
    __shared__ float glds[8][16];     // per-wave row partial sums
    float c_state = 0.f;              // live only for tid < 32
    const int uu = u0 + (tid & 31);

    // xg prefetch registers (gate threads only)
    float xq0 = 0.f, xq1 = 0.f, xq2 = 0.f, xq3 = 0.f;
    if (tid < 32) {
        const float* xgt = xg + (size_t)(dir ? (L - 1) : 0) * G4;
        xq0 = xgt[uu];            xq1 = xgt[HH + uu];
        xq2 = xgt[2 * HH + uu];   xq3 = xgt[3 * HH + uu];
    }

    for (int s = 0; s < L; s++) {
        const int t = dir ? (L - 1 - s) : s;
        const int p = s & 1;

        // A/B: poll my single word of h[t-1], deposit into LDS
        unsigned int v = 0;           // s==0: h = 0
        if (s > 0) {
            const int tp = dir ? (t + 1) : (t - 1);
            const unsigned int* hp =
                (const unsigned int*)(hout + (size_t)tp * HH) + tid;
            do {
                v = __hip_atomic_load(hp, __ATOMIC_RELAXED,
                                      __HIP_MEMORY_SCOPE_AGENT);
            } while (v == SENT);
        }
        h_lds[p][tid] = __uint_as_float(v);
        __syncthreads();                               // barrier 1

        // D: matvec on my 8 cols for my wave's 16 rows
        const float4 h0 = *(const float4*)&h_lds[p][col0];
        const float4 h1 = *(const float4*)&h_lds[p][col0 + 4];
        const float hv[8] = { h0.x, h0.y, h0.z, h0.w, h1.x, h1.y, h1.z, h1.w };

        float acc[16];
#pragma unroll
        for (int rr = 0; rr < 16; rr++) {
            float a = 0.f;
#pragma unroll
            for (int k = 0; k < 8; k++) a += w[rr][k] * hv[k];
            acc[rr] = a;
        }

        // register-compacting butterfly reduction across 64 lanes
        {
            const bool b0 = lane & 1;
#pragma unroll
            for (int r = 0; r < 8; r++) {
                const float send = b0 ? acc[r] : acc[r + 8];
                const float recv = __shfl_xor(send, 1, 64);
                acc[r] = (b0 ? acc[r + 8] : acc[r]) + recv;
            }
            const bool b1 = lane & 2;
#pragma unroll
            for (int r = 0; r < 4; r++) {
                const float send = b1 ? acc[r] : acc[r + 4];
                const float recv = __shfl_xor(send, 2, 64);
                acc[r] = (b1 ? acc[r + 4] : acc[r]) + recv;
            }
            const bool b2 = lane & 4;
#pragma unroll
            for (int r = 0; r < 2; r++) {
                const float send = b2 ? acc[r] : acc[r + 2];
                const float recv = __shfl_xor(send, 4, 64);
                acc[r] = (b2 ? acc[r + 2] : acc[r]) + recv;
            }
            const bool b3 = lane & 8;
            {
                const float send = b3 ? acc[0] : acc[1];
                const float recv = __shfl_xor(send, 8, 64);
                acc[0] = (b3 ? acc[1] : acc[0]) + recv;
            }
            acc[0] += __shfl_xor(acc[0], 16, 64);
            acc[0] += __shfl_xor(acc[0], 32, 64);
        }
        // lane l (<16) holds local row R = 8*b0 + 4*b1 + 2*b2 + b3 (bit-rev)
        if (lane < 16) {
            const int R = ((lane & 1) << 3) | ((lane & 2) << 1) |
                          ((lane & 4) >> 1) | ((lane & 8) >> 3);
            glds[wave][R] = acc[0];
        }
        __syncthreads();                               // barrier 2

        // F: gate math + h store (32 gate threads)
        if (tid < 32) {
            const int j   = tid;         // unit within block
            const int jh_ = j >> 4;      // half
            const int rr  = j & 15;
            float iv = glds[0 + jh_][rr] + xq0;
            float fv = glds[2 + jh_][rr] + xq1;
            float gv = glds[4 + jh_][rr] + xq2;
            float ov = glds[6 + jh_][rr] + xq3;
            iv = 1.f / (1.f + expf(-iv));
            fv = 1.f / (1.f + expf(-fv));
            gv = tanhf(gv);
            ov = 1.f / (1.f + expf(-ov));
            c_state = fv * c_state + iv * gv;
            const float hval = ov * tanhf(c_state);
            __hip_atomic_store((unsigned int*)&hout[(size_t)t * HH + uu],
                               __float_as_uint(hval), __ATOMIC_RELAXED,
                               __HIP_MEMORY_SCOPE_AGENT);
            // prefetch next step's xg (hides under next poll + matvec)
            if (s + 1 < L) {
                const int tn = dir ? (t - 1) : (t + 1);
                const float* xgt = xg + (size_t)tn * G4;
                xq0 = xgt[uu];            xq1 = xgt[HH + uu];
                xq2 = xgt[2 * HH + uu];   xq3 = xgt[3 * HH + uu];
            }
        }
        // no trailing barrier: next iteration writes h_lds[p^1] (ping-pong),
        // and glds is only rewritten after the next barrier 1.
    }
}

// ---------------------------------------------------------------------------
// Kernel 3: feats[t][i] = [hf[t],hb[t]] . w_out[i] + b_out[i]
// grid L blocks, block 256.  feats stored with stride 8.
// ---------------------------------------------------------------------------
__global__ __launch_bounds__(256)
void feats_kernel(const float* __restrict__ hf, const float* __restrict__ hb,
                  const float* __restrict__ wout, const float* __restrict__ bout,
                  float* __restrict__ feats)
{
    const int t   = blockIdx.x;
    const int tid = threadIdx.x;

    float acc[T_TAG];
#pragma unroll
    for (int i = 0; i < T_TAG; i++) acc[i] = 0.f;

    for (int c = tid; c < HID; c += 256) {
        const float v = (c < HH) ? hf[(size_t)t * HH + c]
                                 : hb[(size_t)t * HH + (c - HH)];
#pragma unroll
        for (int i = 0; i < T_TAG; i++) acc[i] += v * wout[i * HID + c];
    }
#pragma unroll
    for (int m = 1; m < 64; m <<= 1) {
#pragma unroll
        for (int i = 0; i < T_TAG; i++) acc[i] += __shfl_xor(acc[i], m, 64);
    }

    __shared__ float red[4][T_TAG];
    const int wave = tid >> 6, lane = tid & 63;
    if (lane == 0) {
#pragma unroll
        for (int i = 0; i < T_TAG; i++) red[wave][i] = acc[i];
    }
    __syncthreads();
    if (tid < T_TAG) {
        feats[(size_t)t * 8 + tid] =
            red[0][tid] + red[1][tid] + red[2][tid] + red[3][tid] + bout[tid];
    }
}

// ---------------------------------------------------------------------------
// Kernel 4: Viterbi forward + backtrace.  One wave.
// ---------------------------------------------------------------------------
__global__ __launch_bounds__(64)
void viterbi_kernel(const float* __restrict__ feats, const float* __restrict__ trans,
                    float* __restrict__ out)
{
    __shared__ unsigned char bp[L][T_TAG];

    const int tid = threadIdx.x;     // 0..63
    const int i = tid >> 3, j = tid & 7;
    const bool valid = (i < T_TAG) && (j < T_TAG);
    const float trij = valid ? trans[i * T_TAG + j] : -1e30f;

    float fv;
    if (j < T_TAG) fv = (j == START_TAG) ? 0.f : NEGV;
    else           fv = -1e30f;

    const int ieff = (i < T_TAG) ? i : 0;
    float fq[8];
#pragma unroll
    for (int p = 0; p < 8; p++) fq[p] = feats[(size_t)p * 8 + ieff];

    for (int t = 0; t < L; t++) {
        const float sc = fv + trij;
        float best = sc; int bj = j;
#pragma unroll
        for (int m = 1; m < 8; m <<= 1) {
            const float ov = __shfl_xor(best, m, 8);
            const int   oj = __shfl_xor(bj, m, 8);
            if (ov > best || (ov == best && oj < bj)) { best = ov; bj = oj; }
        }
        const float f_t = fq[t & 7];
        if (t + 8 < L) fq[t & 7] = feats[(size_t)(t + 8) * 8 + ieff];
        const float fvnew = best + f_t;          // for dest tag == i
        if (valid && j == 0) bp[t][i] = (unsigned char)bj;
        const float nf = __shfl(fvnew, (j < T_TAG) ? j * 8 : 0, 64);
        fv = (j < T_TAG) ? nf : -1e30f;
    }

    float term = fv + ((j < T_TAG) ? trans[STOP_TAG * T_TAG + j] : -1e30f);
    float bestt = term; int bt = j;
#pragma unroll
    for (int m = 1; m < 8; m <<= 1) {
        const float ov = __shfl_xor(bestt, m, 8);
        const int   oj = __shfl_xor(bt, m, 8);
        if (ov > bestt || (ov == bestt && oj < bt)) { bestt = ov; bt = oj; }
    }

    if (tid == 0) {
        out[L] = bestt;
        int tag = bt;
        out[L - 1] = (float)tag;
        for (int t = L - 1; t >= 1; t--) {
            tag = bp[t][tag];
            out[t - 1] = (float)tag;
        }
    }
}

// ---------------------------------------------------------------------------
extern "C" void kernel_launch(void* const* d_in, const int* in_sizes, int n_in,
                              void* d_out, int out_size, void* d_ws, size_t ws_size,
                              hipStream_t stream)
{
    const int*   sentence = (const int*)  d_in[0];
    const float* emb      = (const float*)d_in[1];
    const float* wih_f    = (const float*)d_in[2];
    const float* whh_f    = (const float*)d_in[3];
    const float* bih_f    = (const float*)d_in[4];
    const float* bhh_f    = (const float*)d_in[5];
    const float* wih_b    = (const float*)d_in[6];
    const float* whh_b    = (const float*)d_in[7];
    const float* bih_b    = (const float*)d_in[8];
    const float* bhh_b    = (const float*)d_in[9];
    const float* wout     = (const float*)d_in[10];
    const float* bout     = (const float*)d_in[11];
    const float* trans    = (const float*)d_in[12];
    float* out = (float*)d_out;

    char* ws = (char*)d_ws;
    float* xg_f   = (float*)(ws + 1024);
    float* xg_b   = xg_f  + (size_t)L * G4;
    float* hfbuf  = xg_b  + (size_t)L * G4;
    float* hbbuf  = hfbuf + (size_t)L * HH;
    float* featsb = hbbuf + (size_t)L * HH;
    // total: 1024 + 2*L*G4*4 + 2*L*HH*4 + L*8*4  ~= 84 MB

    // h buffers -> sentinel (0xFF bytes = -NaN); data-arrival sync relies on it
    hipMemsetAsync(hfbuf, 0xFF, (size_t)2 * L * HH * sizeof(float), stream);

    hipLaunchKernelGGL(xg_kernel, dim3(L / 64, G4 / 64, 2), dim3(256), 0, stream,
                       sentence, emb, wih_f, bih_f, bhh_f, wih_b, bih_b, bhh_b,
                       xg_f, xg_b);

    void* args[] = { (void*)&xg_f, (void*)&xg_b, (void*)&whh_f, (void*)&whh_b,
                     (void*)&hfbuf, (void*)&hbbuf };
    hipLaunchCooperativeKernel((void*)lstm_kernel, dim3(2 * NBLK), dim3(512),
                               args, 0, stream);

    hipLaunchKernelGGL(feats_kernel, dim3(L), dim3(256), 0, stream,
                       hfbuf, hbbuf, wout, bout, featsb);

    hipLaunchKernelGGL(viterbi_kernel, dim3(1), dim3(64), 0, stream,
                       featsb, trans, out);
}